// Round 1
// baseline (175.301 us; speedup 1.0000x reference)
//
#include <hip/hip_runtime.h>

#define B_ 4096
#define D_ 256
#define N_ 8192
// log2(e)/0.07
#define EXP2SC 20.60992915555662f

typedef float f32x4 __attribute__((ext_vector_type(4)));
typedef __bf16 bf16x8 __attribute__((ext_vector_type(8)));

__device__ __forceinline__ float fast_exp2(float x){
#if __has_builtin(__builtin_amdgcn_exp2f)
  return __builtin_amdgcn_exp2f(x);
#else
  return exp2f(x);
#endif
}

__device__ __forceinline__ unsigned short f2bf(float x){
  unsigned int u = __float_as_uint(x);
  unsigned int r = (u + 0x7fffu + ((u >> 16) & 1u)) >> 16;
  return (unsigned short)r;
}

// ---------------- kernel 1: pack labels into 80-bit masks ----------------
__global__ __launch_bounds__(256) void pack_kernel(const float* __restrict__ labels,
                                                   ulonglong2* __restrict__ bits,
                                                   int* __restrict__ scnt){
  int i = blockIdx.x * 256 + threadIdx.x;      // 0..4095
  const float* L = labels + (size_t)i * 80;
  unsigned long long lo = 0ull, hi = 0ull;
  #pragma unroll
  for (int c = 0; c < 64; ++c) lo |= (L[c] > 0.5f) ? (1ull << c) : 0ull;
  #pragma unroll
  for (int c = 64; c < 80; ++c) hi |= (L[c] > 0.5f) ? (1ull << (c - 64)) : 0ull;
  bits[i] = make_ulonglong2(lo, hi);
  scnt[i] = __popcll(lo) + __popcll(hi);
}

// ------------- kernel 2: f32 features -> bf16 contrast [N][D] -------------
// contrast[v*B + b][d] = f[b][v][d]
__global__ __launch_bounds__(256) void conv_kernel(const float* __restrict__ f,
                                                   unsigned short* __restrict__ ctr){
  int t = blockIdx.x * 256 + threadIdx.x;      // 0..262143, 8 elems each
  int row = t >> 5;                            // 0..8191
  int dblk = (t & 31) << 3;                    // 0..248
  int v = row >> 12, b = row & 4095;
  const float* src = f + ((((size_t)b << 1) + v) << 8) + dblk;
  float4 a = *(const float4*)src;
  float4 c = *(const float4*)(src + 4);
  uint4 o;
  o.x = (unsigned)f2bf(a.x) | ((unsigned)f2bf(a.y) << 16);
  o.y = (unsigned)f2bf(a.z) | ((unsigned)f2bf(a.w) << 16);
  o.z = (unsigned)f2bf(c.x) | ((unsigned)f2bf(c.y) << 16);
  o.w = (unsigned)f2bf(c.z) | ((unsigned)f2bf(c.w) << 16);
  *(uint4*)(ctr + ((size_t)row << 8) + dblk) = o;
}

// --------- sparse phase-A helpers (pos_sum via scalar bf16 dots) ---------
__device__ float dot_bf16(const unsigned short* a, const unsigned short* b){
  float s = 0.f;
  for (int k = 0; k < 256; k += 8){
    uint4 ua = *(const uint4*)(a + k);
    uint4 ub = *(const uint4*)(b + k);
    const unsigned* pa = (const unsigned*)&ua;
    const unsigned* pb = (const unsigned*)&ub;
    #pragma unroll
    for (int w = 0; w < 4; ++w){
      unsigned x = pa[w], y = pb[w];
      float x0 = __uint_as_float(x << 16), x1 = __uint_as_float(x & 0xffff0000u);
      float y0 = __uint_as_float(y << 16), y1 = __uint_as_float(y & 0xffff0000u);
      s = fmaf(x0, y0, s);
      s = fmaf(x1, y1, s);
    }
  }
  return s;
}

__device__ __noinline__ void phase_a(int i, int jm, const unsigned short* ctr,
                                     float* possum){
  const unsigned short* a = ctr + ((size_t)i << 8);
  float e;
  if (jm == i){
    // self column i is masked; only column B+i contributes
    e = fast_exp2(dot_bf16(a, ctr + ((size_t)(B_ + i) << 8)) * EXP2SC);
  } else {
    float d0 = dot_bf16(a, ctr + ((size_t)jm << 8));
    float d1 = dot_bf16(a, ctr + ((size_t)(B_ + jm) << 8));
    e = fast_exp2(d0 * EXP2SC) + fast_exp2(d1 * EXP2SC);
  }
  atomicAdd(&possum[i], e);
}

// ------ kernel 3: Jaccard pos bits + counts + sparse pos_sum (phase A) ------
// block = 16 anchor rows x all 4096 jm
__global__ __launch_bounds__(256) void pos_kernel(const ulonglong2* __restrict__ bits,
                                                  const int* __restrict__ scnt,
                                                  const unsigned short* __restrict__ ctr,
                                                  float* __restrict__ possum,
                                                  int* __restrict__ poscnt){
  __shared__ unsigned long long rbl[16], rbh[16];
  __shared__ int rs_sh[16];
  __shared__ int cnt_sh[16];
  int tid = threadIdx.x;
  int i0 = blockIdx.x * 16;
  if (tid < 16){
    ulonglong2 bb = bits[i0 + tid];
    rbl[tid] = bb.x; rbh[tid] = bb.y;
    rs_sh[tid] = scnt[i0 + tid];
    cnt_sh[tid] = 0;
  }
  __syncthreads();
  int lc[16];
  #pragma unroll
  for (int r = 0; r < 16; ++r) lc[r] = 0;
  for (int it = 0; it < 16; ++it){
    int jm = it * 256 + tid;
    ulonglong2 bj = bits[jm];
    int sj = scnt[jm];
    #pragma unroll
    for (int r = 0; r < 16; ++r){
      int inter = __popcll(rbl[r] & bj.x) + __popcll(rbh[r] & bj.y);
      int uni = rs_sh[r] + sj - inter;
      if (2 * inter >= uni){                       // cheap prefilter
        // exact reference semantics: inter/(union+1e-6) >= 0.5 in f32
        float sim = (float)inter / ((float)uni + 1e-6f);
        if (sim >= 0.5f){
          lc[r]++;
          phase_a(i0 + r, jm, ctr, possum);
        }
      }
    }
  }
  #pragma unroll
  for (int r = 0; r < 16; ++r){
    int v = lc[r];
    v += __shfl_xor(v, 1);  v += __shfl_xor(v, 2);  v += __shfl_xor(v, 4);
    v += __shfl_xor(v, 8);  v += __shfl_xor(v, 16); v += __shfl_xor(v, 32);
    if ((tid & 63) == 0) atomicAdd(&cnt_sh[r], v);
  }
  __syncthreads();
  if (tid < 16) poscnt[i0 + tid] = cnt_sh[tid];
}

// ---- kernel 4: fused bf16 MFMA GEMM + exp + masked row-total reduction ----
// 128x128 tile, BK=64, 4 waves (2x2), global_load_lds staging, T2 XOR swizzle
#define GLDS16(g, l) __builtin_amdgcn_global_load_lds( \
    (const __attribute__((address_space(1))) unsigned int*)(unsigned long long)(uintptr_t)(g), \
    (__attribute__((address_space(3))) unsigned int*)(unsigned int)(uintptr_t)(l), 16, 0, 0)

__global__ __launch_bounds__(256) void gemm_kernel(const unsigned short* __restrict__ ctr,
                                                   float* __restrict__ total){
  __shared__ __align__(16) char Al[16384];   // 128 rows x 64 k bf16, swizzled
  __shared__ __align__(16) char Bl[16384];
  const int tid  = threadIdx.x;
  const int lane = tid & 63;
  const int w    = tid >> 6;
  const int wm   = w >> 1, wn = w & 1;
  // XCD-aware mapping: each XCD gets 8 contiguous cb + all rb (footprint ~3MB/L2)
  const int bid = (int)blockIdx.x;
  const int cb = (bid & 7) * 8 + ((bid >> 3) & 7);
  const int rb = bid >> 6;                   // 0..31
  const int i0 = rb << 7, n0 = cb << 7;
  const int lr = lane & 15, lk = lane >> 4;

  f32x4 acc[4][4];
  #pragma unroll
  for (int mt = 0; mt < 4; ++mt)
    #pragma unroll
    for (int nt = 0; nt < 4; ++nt)
      acc[mt][nt] = f32x4{0.f, 0.f, 0.f, 0.f};

  for (int ks = 0; ks < 4; ++ks){
    const int k0 = ks << 6;
    if (ks) __syncthreads();                 // protect LDS reuse
    #pragma unroll
    for (int q = 0; q < 4; ++q){
      int c = (w << 2) + q;                  // chunk 0..15 (wave-uniform)
      int row = (c << 3) + (lane >> 3);
      int k16 = (lane & 7) ^ (row & 7);      // inverse-swizzled source (rule 21)
      size_t ga = (((size_t)(i0 + row)) << 8) + k0 + (k16 << 3);
      size_t gb = (((size_t)(n0 + row)) << 8) + k0 + (k16 << 3);
      GLDS16(ctr + ga, Al + (c << 10));
      GLDS16(ctr + gb, Bl + (c << 10));
    }
    __syncthreads();                         // drains vmcnt before reads
    #pragma unroll
    for (int kf = 0; kf < 2; ++kf){
      bf16x8 af[4], bfr[4];
      #pragma unroll
      for (int mt = 0; mt < 4; ++mt){
        int row = (wm << 6) + (mt << 4) + lr;
        int kb  = (kf << 2) + lk;
        af[mt] = *(const bf16x8*)(Al + row * 128 + ((kb ^ (row & 7)) << 4));
      }
      #pragma unroll
      for (int nt = 0; nt < 4; ++nt){
        int row = (wn << 6) + (nt << 4) + lr;
        int kb  = (kf << 2) + lk;
        bfr[nt] = *(const bf16x8*)(Bl + row * 128 + ((kb ^ (row & 7)) << 4));
      }
      #pragma unroll
      for (int mt = 0; mt < 4; ++mt)
        #pragma unroll
        for (int nt = 0; nt < 4; ++nt)
          acc[mt][nt] = __builtin_amdgcn_mfma_f32_16x16x32_bf16(af[mt], bfr[nt],
                                                                acc[mt][nt], 0, 0, 0);
    }
  }

  // epilogue: e = exp2(dot*SC), mask self (grow==gcol), row partial sums
  float rs[4][4];
  #pragma unroll
  for (int mt = 0; mt < 4; ++mt)
    #pragma unroll
    for (int q = 0; q < 4; ++q) rs[mt][q] = 0.f;
  #pragma unroll
  for (int mt = 0; mt < 4; ++mt){
    #pragma unroll
    for (int nt = 0; nt < 4; ++nt){
      int gcol = n0 + (wn << 6) + (nt << 4) + lr;
      #pragma unroll
      for (int q = 0; q < 4; ++q){
        int grow = i0 + (wm << 6) + (mt << 4) + (lk << 2) + q;
        float e = fast_exp2(acc[mt][nt][q] * EXP2SC);
        e = (grow == gcol) ? 0.f : e;
        rs[mt][q] += e;
      }
    }
  }
  #pragma unroll
  for (int mt = 0; mt < 4; ++mt){
    #pragma unroll
    for (int q = 0; q < 4; ++q){
      float v = rs[mt][q];
      v += __shfl_xor(v, 1); v += __shfl_xor(v, 2);
      v += __shfl_xor(v, 4); v += __shfl_xor(v, 8);
      if ((lane & 15) == 0){
        int grow = i0 + (wm << 6) + (mt << 4) + (lk << 2) + q;
        atomicAdd(&total[grow], v);
      }
    }
  }
}

// ---------------- kernel 5: finalize loss ----------------
__global__ __launch_bounds__(1024) void fin_kernel(const float* __restrict__ possum,
                                                   const float* __restrict__ total,
                                                   const int* __restrict__ poscnt,
                                                   const int* __restrict__ scnt,
                                                   float* __restrict__ out){
  int tid = threadIdx.x;
  float ls = 0.f, hc = 0.f;
  #pragma unroll
  for (int k = 0; k < 4; ++k){
    int i = k * 1024 + tid;
    int pii = (scnt[i] > 0) ? 1 : 0;
    int pm = 2 * poscnt[i] - pii;        // pos_m row count (self col removed)
    if (pm > 0){
      float ps = possum[i];
      float neg = total[i] - ps;
      ls += logf((ps + neg + 1e-8f) / ps);
      hc += 1.f;
    }
  }
  ls += __shfl_xor(ls, 1);  ls += __shfl_xor(ls, 2);  ls += __shfl_xor(ls, 4);
  ls += __shfl_xor(ls, 8);  ls += __shfl_xor(ls, 16); ls += __shfl_xor(ls, 32);
  hc += __shfl_xor(hc, 1);  hc += __shfl_xor(hc, 2);  hc += __shfl_xor(hc, 4);
  hc += __shfl_xor(hc, 8);  hc += __shfl_xor(hc, 16); hc += __shfl_xor(hc, 32);
  __shared__ float sl[16], sh[16];
  if ((tid & 63) == 0){ sl[tid >> 6] = ls; sh[tid >> 6] = hc; }
  __syncthreads();
  if (tid == 0){
    float S = 0.f, H = 0.f;
    #pragma unroll
    for (int w2 = 0; w2 < 16; ++w2){ S += sl[w2]; H += sh[w2]; }
    out[0] = S / fmaxf(H, 1.f);
  }
}

extern "C" void kernel_launch(void* const* d_in, const int* in_sizes, int n_in,
                              void* d_out, int out_size, void* d_ws, size_t ws_size,
                              hipStream_t stream){
  (void)in_sizes; (void)n_in; (void)out_size; (void)ws_size;
  const float* feat   = (const float*)d_in[0];
  const float* labels = (const float*)d_in[1];
  float* out = (float*)d_out;
  char* ws = (char*)d_ws;
  unsigned short* ctr = (unsigned short*)(ws);            // 4,194,304 B
  ulonglong2* bits    = (ulonglong2*)(ws + 4194304);      //    65,536 B
  int* scnt           = (int*)(ws + 4259840);             //    16,384 B
  float* possum       = (float*)(ws + 4276224);           //    16,384 B
  float* total        = (float*)(ws + 4292608);           //    16,384 B
  int* poscnt         = (int*)(ws + 4308992);             //    16,384 B

  hipMemsetAsync(possum, 0, 32768, stream);               // possum + total

  hipLaunchKernelGGL(pack_kernel, dim3(16),   dim3(256),  0, stream, labels, bits, scnt);
  hipLaunchKernelGGL(conv_kernel, dim3(1024), dim3(256),  0, stream, feat, ctr);
  hipLaunchKernelGGL(pos_kernel,  dim3(256),  dim3(256),  0, stream, bits, scnt, ctr, possum, poscnt);
  hipLaunchKernelGGL(gemm_kernel, dim3(2048), dim3(256),  0, stream, ctr, total);
  hipLaunchKernelGGL(fin_kernel,  dim3(1),    dim3(1024), 0, stream, possum, total, poscnt, scnt, out);
}

// Round 2
// 165.154 us; speedup vs baseline: 1.0614x; 1.0614x over previous
//
#include <hip/hip_runtime.h>

#define B_ 4096
#define D_ 256
#define N_ 8192
// log2(e)/0.07
#define EXP2SC 20.60992915555662f

typedef float f32x4 __attribute__((ext_vector_type(4)));
typedef __bf16 bf16x8 __attribute__((ext_vector_type(8)));

__device__ __forceinline__ float fast_exp2(float x){
#if __has_builtin(__builtin_amdgcn_exp2f)
  return __builtin_amdgcn_exp2f(x);
#else
  return exp2f(x);
#endif
}

__device__ __forceinline__ unsigned short f2bf(float x){
  unsigned int u = __float_as_uint(x);
  unsigned int r = (u + 0x7fffu + ((u >> 16) & 1u)) >> 16;
  return (unsigned short)r;
}

// ---------------- kernel 1: pack labels into 80-bit masks ----------------
__global__ __launch_bounds__(256) void pack_kernel(const float* __restrict__ labels,
                                                   ulonglong2* __restrict__ bits,
                                                   int* __restrict__ scnt){
  int i = blockIdx.x * 256 + threadIdx.x;      // 0..4095
  const float* L = labels + (size_t)i * 80;
  unsigned long long lo = 0ull, hi = 0ull;
  #pragma unroll
  for (int c = 0; c < 64; ++c) lo |= (L[c] > 0.5f) ? (1ull << c) : 0ull;
  #pragma unroll
  for (int c = 64; c < 80; ++c) hi |= (L[c] > 0.5f) ? (1ull << (c - 64)) : 0ull;
  bits[i] = make_ulonglong2(lo, hi);
  scnt[i] = __popcll(lo) + __popcll(hi);
}

// ------------- kernel 2: f32 features -> bf16 contrast [N][D] -------------
// contrast[v*B + b][d] = f[b][v][d]
__global__ __launch_bounds__(256) void conv_kernel(const float* __restrict__ f,
                                                   unsigned short* __restrict__ ctr){
  int t = blockIdx.x * 256 + threadIdx.x;      // 0..262143, 8 elems each
  int row = t >> 5;                            // 0..8191
  int dblk = (t & 31) << 3;                    // 0..248
  int v = row >> 12, b = row & 4095;
  const float* src = f + ((((size_t)b << 1) + v) << 8) + dblk;
  float4 a = *(const float4*)src;
  float4 c = *(const float4*)(src + 4);
  uint4 o;
  o.x = (unsigned)f2bf(a.x) | ((unsigned)f2bf(a.y) << 16);
  o.y = (unsigned)f2bf(a.z) | ((unsigned)f2bf(a.w) << 16);
  o.z = (unsigned)f2bf(c.x) | ((unsigned)f2bf(c.y) << 16);
  o.w = (unsigned)f2bf(c.z) | ((unsigned)f2bf(c.w) << 16);
  *(uint4*)(ctr + ((size_t)row << 8) + dblk) = o;
}

// --------- sparse phase-A helpers (pos_sum via scalar bf16 dots) ---------
__device__ float dot_bf16(const unsigned short* a, const unsigned short* b){
  float s = 0.f;
  for (int k = 0; k < 256; k += 8){
    uint4 ua = *(const uint4*)(a + k);
    uint4 ub = *(const uint4*)(b + k);
    const unsigned* pa = (const unsigned*)&ua;
    const unsigned* pb = (const unsigned*)&ub;
    #pragma unroll
    for (int w = 0; w < 4; ++w){
      unsigned x = pa[w], y = pb[w];
      float x0 = __uint_as_float(x << 16), x1 = __uint_as_float(x & 0xffff0000u);
      float y0 = __uint_as_float(y << 16), y1 = __uint_as_float(y & 0xffff0000u);
      s = fmaf(x0, y0, s);
      s = fmaf(x1, y1, s);
    }
  }
  return s;
}

__device__ __noinline__ void phase_a(int i, int jm, const unsigned short* ctr,
                                     float* possum){
  const unsigned short* a = ctr + ((size_t)i << 8);
  float e;
  if (jm == i){
    // self column i is masked; only column B+i contributes
    e = fast_exp2(dot_bf16(a, ctr + ((size_t)(B_ + i) << 8)) * EXP2SC);
  } else {
    float d0 = dot_bf16(a, ctr + ((size_t)jm << 8));
    float d1 = dot_bf16(a, ctr + ((size_t)(B_ + jm) << 8));
    e = fast_exp2(d0 * EXP2SC) + fast_exp2(d1 * EXP2SC);
  }
  atomicAdd(&possum[i], e);
}

// ------ kernel 3: Jaccard pos bits + counts + sparse pos_sum (phase A) ------
// grid = 4096 blocks: 256 row-groups (16 rows) x 16 jm-chunks (256 jm each).
// One jm per thread -> hit flag per (r, thread) -> wave ballot for counts.
__global__ __launch_bounds__(256) void pos_kernel(const ulonglong2* __restrict__ bits,
                                                  const int* __restrict__ scnt,
                                                  const unsigned short* __restrict__ ctr,
                                                  float* __restrict__ possum,
                                                  int* __restrict__ poscnt){
  __shared__ unsigned long long rbl[16], rbh[16];
  __shared__ int rs_sh[16];
  int tid = threadIdx.x;
  int bid = blockIdx.x;
  int i0 = (bid >> 4) << 4;                   // row group base
  int jm = ((bid & 15) << 8) + tid;           // this thread's column
  if (tid < 16){
    ulonglong2 bb = bits[i0 + tid];
    rbl[tid] = bb.x; rbh[tid] = bb.y;
    rs_sh[tid] = scnt[i0 + tid];
  }
  __syncthreads();
  ulonglong2 bj = bits[jm];
  int sj = scnt[jm];
  int lane = tid & 63;
  #pragma unroll
  for (int r = 0; r < 16; ++r){
    int inter = __popcll(rbl[r] & bj.x) + __popcll(rbh[r] & bj.y);
    int uni = rs_sh[r] + sj - inter;
    bool hit = false;
    if (2 * inter >= uni){                     // integer prefilter (superset)
      // exact reference semantics: inter/(union+1e-6) >= 0.5 in f32
      float sim = (float)inter / ((float)uni + 1e-6f);
      hit = (sim >= 0.5f);
    }
    unsigned long long m = __ballot(hit);
    if (hit) phase_a(i0 + r, jm, ctr, possum);
    if (lane == 0 && m) atomicAdd(&poscnt[i0 + r], __popcll(m));
  }
}

// ---- kernel 4: fused bf16 MFMA GEMM + exp + masked row-total reduction ----
// 128x128 tile, BK=64, 4 waves (2x2), global_load_lds staging, T2 XOR swizzle
#define GLDS16(g, l) __builtin_amdgcn_global_load_lds( \
    (const __attribute__((address_space(1))) unsigned int*)(unsigned long long)(uintptr_t)(g), \
    (__attribute__((address_space(3))) unsigned int*)(unsigned int)(uintptr_t)(l), 16, 0, 0)

__global__ __launch_bounds__(256) void gemm_kernel(const unsigned short* __restrict__ ctr,
                                                   float* __restrict__ total){
  __shared__ __align__(16) char Al[16384];   // 128 rows x 64 k bf16, swizzled
  __shared__ __align__(16) char Bl[16384];
  const int tid  = threadIdx.x;
  const int lane = tid & 63;
  const int w    = tid >> 6;
  const int wm   = w >> 1, wn = w & 1;
  // XCD-aware mapping: each XCD gets 8 contiguous cb + all rb
  const int bid = (int)blockIdx.x;
  const int cb = (bid & 7) * 8 + ((bid >> 3) & 7);
  const int rb = bid >> 6;                   // 0..31
  const int i0 = rb << 7, n0 = cb << 7;
  const int lr = lane & 15, lk = lane >> 4;

  f32x4 acc[4][4];
  #pragma unroll
  for (int mt = 0; mt < 4; ++mt)
    #pragma unroll
    for (int nt = 0; nt < 4; ++nt)
      acc[mt][nt] = f32x4{0.f, 0.f, 0.f, 0.f};

  for (int ks = 0; ks < 4; ++ks){
    const int k0 = ks << 6;
    if (ks) __syncthreads();                 // protect LDS reuse
    #pragma unroll
    for (int q = 0; q < 4; ++q){
      int c = (w << 2) + q;                  // chunk 0..15 (wave-uniform)
      int row = (c << 3) + (lane >> 3);
      int k16 = (lane & 7) ^ (row & 7);      // inverse-swizzled source (rule 21)
      size_t ga = (((size_t)(i0 + row)) << 8) + k0 + (k16 << 3);
      size_t gb = (((size_t)(n0 + row)) << 8) + k0 + (k16 << 3);
      GLDS16(ctr + ga, Al + (c << 10));
      GLDS16(ctr + gb, Bl + (c << 10));
    }
    __syncthreads();                         // drains vmcnt before reads
    #pragma unroll
    for (int kf = 0; kf < 2; ++kf){
      bf16x8 af[4], bfr[4];
      #pragma unroll
      for (int mt = 0; mt < 4; ++mt){
        int row = (wm << 6) + (mt << 4) + lr;
        int kb  = (kf << 2) + lk;
        af[mt] = *(const bf16x8*)(Al + row * 128 + ((kb ^ (row & 7)) << 4));
      }
      #pragma unroll
      for (int nt = 0; nt < 4; ++nt){
        int row = (wn << 6) + (nt << 4) + lr;
        int kb  = (kf << 2) + lk;
        bfr[nt] = *(const bf16x8*)(Bl + row * 128 + ((kb ^ (row & 7)) << 4));
      }
      #pragma unroll
      for (int mt = 0; mt < 4; ++mt)
        #pragma unroll
        for (int nt = 0; nt < 4; ++nt)
          acc[mt][nt] = __builtin_amdgcn_mfma_f32_16x16x32_bf16(af[mt], bfr[nt],
                                                                acc[mt][nt], 0, 0, 0);
    }
  }

  // epilogue: e = exp2(dot*SC), mask self (grow==gcol), row partial sums
  float rs[4][4];
  #pragma unroll
  for (int mt = 0; mt < 4; ++mt)
    #pragma unroll
    for (int q = 0; q < 4; ++q) rs[mt][q] = 0.f;
  #pragma unroll
  for (int mt = 0; mt < 4; ++mt){
    #pragma unroll
    for (int nt = 0; nt < 4; ++nt){
      int gcol = n0 + (wn << 6) + (nt << 4) + lr;
      #pragma unroll
      for (int q = 0; q < 4; ++q){
        int grow = i0 + (wm << 6) + (mt << 4) + (lk << 2) + q;
        float e = fast_exp2(acc[mt][nt][q] * EXP2SC);
        e = (grow == gcol) ? 0.f : e;
        rs[mt][q] += e;
      }
    }
  }
  #pragma unroll
  for (int mt = 0; mt < 4; ++mt){
    #pragma unroll
    for (int q = 0; q < 4; ++q){
      float v = rs[mt][q];
      v += __shfl_xor(v, 1); v += __shfl_xor(v, 2);
      v += __shfl_xor(v, 4); v += __shfl_xor(v, 8);
      if ((lane & 15) == 0){
        int grow = i0 + (wm << 6) + (mt << 4) + (lk << 2) + q;
        atomicAdd(&total[grow], v);
      }
    }
  }
}

// ---------------- kernel 5: finalize loss ----------------
__global__ __launch_bounds__(1024) void fin_kernel(const float* __restrict__ possum,
                                                   const float* __restrict__ total,
                                                   const int* __restrict__ poscnt,
                                                   const int* __restrict__ scnt,
                                                   float* __restrict__ out){
  int tid = threadIdx.x;
  float ls = 0.f, hc = 0.f;
  #pragma unroll
  for (int k = 0; k < 4; ++k){
    int i = k * 1024 + tid;
    int pii = (scnt[i] > 0) ? 1 : 0;
    int pm = 2 * poscnt[i] - pii;        // pos_m row count (self col removed)
    if (pm > 0){
      float ps = possum[i];
      float neg = total[i] - ps;
      ls += logf((ps + neg + 1e-8f) / ps);
      hc += 1.f;
    }
  }
  ls += __shfl_xor(ls, 1);  ls += __shfl_xor(ls, 2);  ls += __shfl_xor(ls, 4);
  ls += __shfl_xor(ls, 8);  ls += __shfl_xor(ls, 16); ls += __shfl_xor(ls, 32);
  hc += __shfl_xor(hc, 1);  hc += __shfl_xor(hc, 2);  hc += __shfl_xor(hc, 4);
  hc += __shfl_xor(hc, 8);  hc += __shfl_xor(hc, 16); hc += __shfl_xor(hc, 32);
  __shared__ float sl[16], sh[16];
  if ((tid & 63) == 0){ sl[tid >> 6] = ls; sh[tid >> 6] = hc; }
  __syncthreads();
  if (tid == 0){
    float S = 0.f, H = 0.f;
    #pragma unroll
    for (int w2 = 0; w2 < 16; ++w2){ S += sl[w2]; H += sh[w2]; }
    out[0] = S / fmaxf(H, 1.f);
  }
}

extern "C" void kernel_launch(void* const* d_in, const int* in_sizes, int n_in,
                              void* d_out, int out_size, void* d_ws, size_t ws_size,
                              hipStream_t stream){
  (void)in_sizes; (void)n_in; (void)out_size; (void)ws_size;
  const float* feat   = (const float*)d_in[0];
  const float* labels = (const float*)d_in[1];
  float* out = (float*)d_out;
  char* ws = (char*)d_ws;
  unsigned short* ctr = (unsigned short*)(ws);            // 4,194,304 B
  ulonglong2* bits    = (ulonglong2*)(ws + 4194304);      //    65,536 B
  int* scnt           = (int*)(ws + 4259840);             //    16,384 B
  float* possum       = (float*)(ws + 4276224);           //    16,384 B
  float* total        = (float*)(ws + 4292608);           //    16,384 B
  int* poscnt         = (int*)(ws + 4308992);             //    16,384 B

  // possum + total + poscnt are contiguous: one async zero-fill
  hipMemsetAsync(possum, 0, 49152, stream);

  hipLaunchKernelGGL(pack_kernel, dim3(16),   dim3(256),  0, stream, labels, bits, scnt);
  hipLaunchKernelGGL(conv_kernel, dim3(1024), dim3(256),  0, stream, feat, ctr);
  hipLaunchKernelGGL(pos_kernel,  dim3(4096), dim3(256),  0, stream, bits, scnt, ctr, possum, poscnt);
  hipLaunchKernelGGL(gemm_kernel, dim3(2048), dim3(256),  0, stream, ctr, total);
  hipLaunchKernelGGL(fin_kernel,  dim3(1),    dim3(1024), 0, stream, possum, total, poscnt, scnt, out);
}

// Round 3
// 108.986 us; speedup vs baseline: 1.6085x; 1.5154x over previous
//
#include <hip/hip_runtime.h>

#define B_ 4096
#define D_ 256
#define N_ 8192
// log2(e)/0.07
#define EXP2SC 20.60992915555662f

typedef float f32x4 __attribute__((ext_vector_type(4)));
typedef __bf16 bf16x8 __attribute__((ext_vector_type(8)));

__device__ __forceinline__ float fast_exp2(float x){
#if __has_builtin(__builtin_amdgcn_exp2f)
  return __builtin_amdgcn_exp2f(x);
#else
  return exp2f(x);
#endif
}

__device__ __forceinline__ unsigned short f2bf(float x){
  unsigned int u = __float_as_uint(x);
  unsigned int r = (u + 0x7fffu + ((u >> 16) & 1u)) >> 16;
  return (unsigned short)r;
}

// ---------------- kernel 1: pack labels into 80-bit masks ----------------
__global__ __launch_bounds__(256) void pack_kernel(const float* __restrict__ labels,
                                                   ulonglong2* __restrict__ bits,
                                                   int* __restrict__ scnt){
  int i = blockIdx.x * 256 + threadIdx.x;      // 0..4095
  const float* L = labels + (size_t)i * 80;
  unsigned long long lo = 0ull, hi = 0ull;
  #pragma unroll
  for (int c = 0; c < 64; ++c) lo |= (L[c] > 0.5f) ? (1ull << c) : 0ull;
  #pragma unroll
  for (int c = 64; c < 80; ++c) hi |= (L[c] > 0.5f) ? (1ull << (c - 64)) : 0ull;
  bits[i] = make_ulonglong2(lo, hi);
  scnt[i] = __popcll(lo) + __popcll(hi);
}

// ------------- kernel 2: f32 features -> bf16 contrast [N][D] -------------
// contrast[v*B + b][d] = f[b][v][d]
__global__ __launch_bounds__(256) void conv_kernel(const float* __restrict__ f,
                                                   unsigned short* __restrict__ ctr){
  int t = blockIdx.x * 256 + threadIdx.x;      // 0..262143, 8 elems each
  int row = t >> 5;                            // 0..8191
  int dblk = (t & 31) << 3;                    // 0..248
  int v = row >> 12, b = row & 4095;
  const float* src = f + ((((size_t)b << 1) + v) << 8) + dblk;
  float4 a = *(const float4*)src;
  float4 c = *(const float4*)(src + 4);
  uint4 o;
  o.x = (unsigned)f2bf(a.x) | ((unsigned)f2bf(a.y) << 16);
  o.y = (unsigned)f2bf(a.z) | ((unsigned)f2bf(a.w) << 16);
  o.z = (unsigned)f2bf(c.x) | ((unsigned)f2bf(c.y) << 16);
  o.w = (unsigned)f2bf(c.z) | ((unsigned)f2bf(c.w) << 16);
  *(uint4*)(ctr + ((size_t)row << 8) + dblk) = o;
}

// ------ kernel 3: Jaccard pos bitmask (pure bit-math, ballot -> u64) ------
// grid = 4096 blocks: 256 row-groups (16 rows) x 16 jm-chunks (256 jm each).
// No atomics, no dot products: wave ballot -> one u64 store per (row, word).
__global__ __launch_bounds__(256) void pos_kernel(const ulonglong2* __restrict__ bits,
                                                  const int* __restrict__ scnt,
                                                  unsigned long long* __restrict__ posw){
  __shared__ unsigned long long rbl[16], rbh[16];
  __shared__ int rs_sh[16];
  int tid = threadIdx.x;
  int bid = blockIdx.x;
  int i0 = (bid >> 4) << 4;                   // row group base
  int jm = ((bid & 15) << 8) + tid;           // this thread's column
  if (tid < 16){
    ulonglong2 bb = bits[i0 + tid];
    rbl[tid] = bb.x; rbh[tid] = bb.y;
    rs_sh[tid] = scnt[i0 + tid];
  }
  __syncthreads();
  ulonglong2 bj = bits[jm];
  int sj = scnt[jm];
  int lane = tid & 63;
  int wword = ((bid & 15) << 2) + (tid >> 6); // jm >> 6
  #pragma unroll
  for (int r = 0; r < 16; ++r){
    int inter = __popcll(rbl[r] & bj.x) + __popcll(rbh[r] & bj.y);
    int uni = rs_sh[r] + sj - inter;
    bool hit = false;
    if (2 * inter >= uni){                     // integer prefilter (superset)
      // exact reference semantics: inter/(union+1e-6) >= 0.5 in f32
      float sim = (float)inter / ((float)uni + 1e-6f);
      hit = (sim >= 0.5f);
    }
    unsigned long long m = __ballot(hit);
    if (lane == 0) posw[(size_t)(i0 + r) * 64 + wword] = m;
  }
}

// -------- kernel 3b: per-row popcount of pos bitmask (no atomics) --------
__global__ __launch_bounds__(256) void cnt_kernel(const unsigned long long* __restrict__ posw,
                                                  int* __restrict__ poscnt){
  int i = blockIdx.x * 256 + threadIdx.x;     // 0..4095
  const ulonglong2* p = (const ulonglong2*)(posw + (size_t)i * 64);
  int s = 0;
  #pragma unroll
  for (int k = 0; k < 32; ++k){
    ulonglong2 v = p[k];
    s += __popcll(v.x) + __popcll(v.y);
  }
  poscnt[i] = s;
}

// ---- kernel 4: fused bf16 MFMA GEMM + exp + masked row sums (tot & pos) ----
// 128x128 tile, BK=64, 4 waves (2x2), global_load_lds staging, T2 XOR swizzle
#define GLDS16(g, l) __builtin_amdgcn_global_load_lds( \
    (const __attribute__((address_space(1))) unsigned int*)(unsigned long long)(uintptr_t)(g), \
    (__attribute__((address_space(3))) unsigned int*)(unsigned int)(uintptr_t)(l), 16, 0, 0)

__global__ __launch_bounds__(256) void gemm_kernel(const unsigned short* __restrict__ ctr,
                                                   const unsigned long long* __restrict__ posw,
                                                   float* __restrict__ total,
                                                   float* __restrict__ possum){
  __shared__ __align__(16) char Al[16384];   // 128 rows x 64 k bf16, swizzled
  __shared__ __align__(16) char Bl[16384];
  const int tid  = threadIdx.x;
  const int lane = tid & 63;
  const int w    = tid >> 6;
  const int wm   = w >> 1, wn = w & 1;
  // XCD-aware mapping: each XCD gets 8 contiguous cb + all rb
  const int bid = (int)blockIdx.x;
  const int cb = (bid & 7) * 8 + ((bid >> 3) & 7);
  const int rb = bid >> 6;                   // 0..31
  const int i0 = rb << 7, n0 = cb << 7;
  const int lr = lane & 15, lk = lane >> 4;

  f32x4 acc[4][4];
  #pragma unroll
  for (int mt = 0; mt < 4; ++mt)
    #pragma unroll
    for (int nt = 0; nt < 4; ++nt)
      acc[mt][nt] = f32x4{0.f, 0.f, 0.f, 0.f};

  for (int ks = 0; ks < 4; ++ks){
    const int k0 = ks << 6;
    if (ks) __syncthreads();                 // protect LDS reuse
    #pragma unroll
    for (int q = 0; q < 4; ++q){
      int c = (w << 2) + q;                  // chunk 0..15 (wave-uniform)
      int row = (c << 3) + (lane >> 3);
      int k16 = (lane & 7) ^ (row & 7);      // inverse-swizzled source (rule 21)
      size_t ga = (((size_t)(i0 + row)) << 8) + k0 + (k16 << 3);
      size_t gb = (((size_t)(n0 + row)) << 8) + k0 + (k16 << 3);
      GLDS16(ctr + ga, Al + (c << 10));
      GLDS16(ctr + gb, Bl + (c << 10));
    }
    __syncthreads();                         // drains vmcnt before reads
    #pragma unroll
    for (int kf = 0; kf < 2; ++kf){
      bf16x8 af[4], bfr[4];
      #pragma unroll
      for (int mt = 0; mt < 4; ++mt){
        int row = (wm << 6) + (mt << 4) + lr;
        int kb  = (kf << 2) + lk;
        af[mt] = *(const bf16x8*)(Al + row * 128 + ((kb ^ (row & 7)) << 4));
      }
      #pragma unroll
      for (int nt = 0; nt < 4; ++nt){
        int row = (wn << 6) + (nt << 4) + lr;
        int kb  = (kf << 2) + lk;
        bfr[nt] = *(const bf16x8*)(Bl + row * 128 + ((kb ^ (row & 7)) << 4));
      }
      #pragma unroll
      for (int mt = 0; mt < 4; ++mt)
        #pragma unroll
        for (int nt = 0; nt < 4; ++nt)
          acc[mt][nt] = __builtin_amdgcn_mfma_f32_16x16x32_bf16(af[mt], bfr[nt],
                                                                acc[mt][nt], 0, 0, 0);
    }
  }

  // epilogue: e = exp2(dot*SC), self-mask, accumulate total & pos row sums.
  // The 64-col span [n0+wn*64, +64) is 64-aligned -> ONE posw word per row.
  const int widx = ((n0 + (wn << 6)) & 4095) >> 6;
  float rs[4][4], rp[4][4];
  #pragma unroll
  for (int mt = 0; mt < 4; ++mt){
    #pragma unroll
    for (int q = 0; q < 4; ++q){
      int grow = i0 + (wm << 6) + (mt << 4) + (lk << 2) + q;
      unsigned long long w64 = posw[(size_t)grow * 64 + widx];
      float st = 0.f, sp = 0.f;
      #pragma unroll
      for (int nt = 0; nt < 4; ++nt){
        int gcol = n0 + (wn << 6) + (nt << 4) + lr;
        float e = fast_exp2(acc[mt][nt][q] * EXP2SC);
        e = (grow == gcol) ? 0.f : e;
        st += e;
        sp += ((w64 >> ((nt << 4) + lr)) & 1ull) ? e : 0.f;
      }
      rs[mt][q] = st; rp[mt][q] = sp;
    }
  }
  #pragma unroll
  for (int mt = 0; mt < 4; ++mt){
    #pragma unroll
    for (int q = 0; q < 4; ++q){
      float v = rs[mt][q], u = rp[mt][q];
      v += __shfl_xor(v, 1); u += __shfl_xor(u, 1);
      v += __shfl_xor(v, 2); u += __shfl_xor(u, 2);
      v += __shfl_xor(v, 4); u += __shfl_xor(u, 4);
      v += __shfl_xor(v, 8); u += __shfl_xor(u, 8);
      if ((lane & 15) == 0){
        int grow = i0 + (wm << 6) + (mt << 4) + (lk << 2) + q;
        atomicAdd(&total[grow], v);
        if (u != 0.f) atomicAdd(&possum[grow], u);
      }
    }
  }
}

// ---------------- kernel 5: finalize loss ----------------
__global__ __launch_bounds__(1024) void fin_kernel(const float* __restrict__ possum,
                                                   const float* __restrict__ total,
                                                   const int* __restrict__ poscnt,
                                                   const int* __restrict__ scnt,
                                                   float* __restrict__ out){
  int tid = threadIdx.x;
  float ls = 0.f, hc = 0.f;
  #pragma unroll
  for (int k = 0; k < 4; ++k){
    int i = k * 1024 + tid;
    int pii = (scnt[i] > 0) ? 1 : 0;
    int pm = 2 * poscnt[i] - pii;        // pos_m row count (self col removed)
    if (pm > 0){
      float ps = possum[i];
      float neg = total[i] - ps;
      ls += logf((ps + neg + 1e-8f) / ps);
      hc += 1.f;
    }
  }
  ls += __shfl_xor(ls, 1);  ls += __shfl_xor(ls, 2);  ls += __shfl_xor(ls, 4);
  ls += __shfl_xor(ls, 8);  ls += __shfl_xor(ls, 16); ls += __shfl_xor(ls, 32);
  hc += __shfl_xor(hc, 1);  hc += __shfl_xor(hc, 2);  hc += __shfl_xor(hc, 4);
  hc += __shfl_xor(hc, 8);  hc += __shfl_xor(hc, 16); hc += __shfl_xor(hc, 32);
  __shared__ float sl[16], sh[16];
  if ((tid & 63) == 0){ sl[tid >> 6] = ls; sh[tid >> 6] = hc; }
  __syncthreads();
  if (tid == 0){
    float S = 0.f, H = 0.f;
    #pragma unroll
    for (int w2 = 0; w2 < 16; ++w2){ S += sl[w2]; H += sh[w2]; }
    out[0] = S / fmaxf(H, 1.f);
  }
}

extern "C" void kernel_launch(void* const* d_in, const int* in_sizes, int n_in,
                              void* d_out, int out_size, void* d_ws, size_t ws_size,
                              hipStream_t stream){
  (void)in_sizes; (void)n_in; (void)out_size; (void)ws_size;
  const float* feat   = (const float*)d_in[0];
  const float* labels = (const float*)d_in[1];
  float* out = (float*)d_out;
  char* ws = (char*)d_ws;
  unsigned short* ctr       = (unsigned short*)(ws);           // 4,194,304 B
  unsigned long long* posw  = (unsigned long long*)(ws + 4194304); // 2,097,152 B
  ulonglong2* bits          = (ulonglong2*)(ws + 6291456);     //    65,536 B
  int* scnt                 = (int*)(ws + 6356992);            //    16,384 B
  float* possum             = (float*)(ws + 6373376);          //    16,384 B
  float* total              = (float*)(ws + 6389760);          //    16,384 B
  int* poscnt               = (int*)(ws + 6406144);            //    16,384 B

  // possum + total + poscnt contiguous: one async zero-fill
  hipMemsetAsync(possum, 0, 49152, stream);

  hipLaunchKernelGGL(pack_kernel, dim3(16),   dim3(256),  0, stream, labels, bits, scnt);
  hipLaunchKernelGGL(conv_kernel, dim3(1024), dim3(256),  0, stream, feat, ctr);
  hipLaunchKernelGGL(pos_kernel,  dim3(4096), dim3(256),  0, stream, bits, scnt, posw);
  hipLaunchKernelGGL(cnt_kernel,  dim3(16),   dim3(256),  0, stream, posw, poscnt);
  hipLaunchKernelGGL(gemm_kernel, dim3(2048), dim3(256),  0, stream, ctr, posw, total, possum);
  hipLaunchKernelGGL(fin_kernel,  dim3(1),    dim3(1024), 0, stream, possum, total, poscnt, scnt, out);
}

// Round 6
// 91.837 us; speedup vs baseline: 1.9088x; 1.1867x over previous
//
#include <hip/hip_runtime.h>

#define B_ 4096
#define D_ 256
#define N_ 8192
// log2(e)/0.07
#define EXP2SC 20.60992915555662f

typedef float f32x4 __attribute__((ext_vector_type(4)));
typedef __bf16 bf16x8 __attribute__((ext_vector_type(8)));

__device__ __forceinline__ float fast_exp2(float x){
#if __has_builtin(__builtin_amdgcn_exp2f)
  return __builtin_amdgcn_exp2f(x);
#else
  return exp2f(x);
#endif
}

__device__ __forceinline__ unsigned short f2bf(float x){
  unsigned int u = __float_as_uint(x);
  unsigned int r = (u + 0x7fffu + ((u >> 16) & 1u)) >> 16;
  return (unsigned short)r;
}

// ---------------- kernel 1: pack labels into 80-bit masks ----------------
__global__ __launch_bounds__(256) void pack_kernel(const float* __restrict__ labels,
                                                   ulonglong2* __restrict__ bits,
                                                   int* __restrict__ scnt){
  int i = blockIdx.x * 256 + threadIdx.x;      // 0..4095
  const float* L = labels + (size_t)i * 80;
  unsigned long long lo = 0ull, hi = 0ull;
  #pragma unroll
  for (int c = 0; c < 64; ++c) lo |= (L[c] > 0.5f) ? (1ull << c) : 0ull;
  #pragma unroll
  for (int c = 64; c < 80; ++c) hi |= (L[c] > 0.5f) ? (1ull << (c - 64)) : 0ull;
  bits[i] = make_ulonglong2(lo, hi);
  scnt[i] = __popcll(lo) + __popcll(hi);
}

// ------------- kernel 2: f32 features -> bf16 contrast [N][D] -------------
// contrast[v*B + b][d] = f[b][v][d]
__global__ __launch_bounds__(256) void conv_kernel(const float* __restrict__ f,
                                                   unsigned short* __restrict__ ctr){
  int t = blockIdx.x * 256 + threadIdx.x;      // 0..262143, 8 elems each
  int row = t >> 5;                            // 0..8191
  int dblk = (t & 31) << 3;                    // 0..248
  int v = row >> 12, b = row & 4095;
  const float* src = f + ((((size_t)b << 1) + v) << 8) + dblk;
  float4 a = *(const float4*)src;
  float4 c = *(const float4*)(src + 4);
  uint4 o;
  o.x = (unsigned)f2bf(a.x) | ((unsigned)f2bf(a.y) << 16);
  o.y = (unsigned)f2bf(a.z) | ((unsigned)f2bf(a.w) << 16);
  o.z = (unsigned)f2bf(c.x) | ((unsigned)f2bf(c.y) << 16);
  o.w = (unsigned)f2bf(c.z) | ((unsigned)f2bf(c.w) << 16);
  *(uint4*)(ctr + ((size_t)row << 8) + dblk) = o;
}

// ------ kernel 3: Jaccard pos bitmask (pure bit-math, ballot -> u64) ------
__global__ __launch_bounds__(256) void pos_kernel(const ulonglong2* __restrict__ bits,
                                                  const int* __restrict__ scnt,
                                                  unsigned long long* __restrict__ posw){
  __shared__ unsigned long long rbl[16], rbh[16];
  __shared__ int rs_sh[16];
  int tid = threadIdx.x;
  int bid = blockIdx.x;
  int i0 = (bid >> 4) << 4;                   // row group base
  int jm = ((bid & 15) << 8) + tid;           // this thread's column
  if (tid < 16){
    ulonglong2 bb = bits[i0 + tid];
    rbl[tid] = bb.x; rbh[tid] = bb.y;
    rs_sh[tid] = scnt[i0 + tid];
  }
  __syncthreads();
  ulonglong2 bj = bits[jm];
  int sj = scnt[jm];
  int lane = tid & 63;
  int wword = ((bid & 15) << 2) + (tid >> 6); // jm >> 6
  #pragma unroll
  for (int r = 0; r < 16; ++r){
    int inter = __popcll(rbl[r] & bj.x) + __popcll(rbh[r] & bj.y);
    int uni = rs_sh[r] + sj - inter;
    bool hit = false;
    if (2 * inter >= uni){                     // integer prefilter (superset)
      float sim = (float)inter / ((float)uni + 1e-6f);
      hit = (sim >= 0.5f);
    }
    unsigned long long m = __ballot(hit);
    if (lane == 0) posw[(size_t)(i0 + r) * 64 + wword] = m;
  }
}

// -------- kernel 3b: per-row popcount of pos bitmask (no atomics) --------
__global__ __launch_bounds__(256) void cnt_kernel(const unsigned long long* __restrict__ posw,
                                                  int* __restrict__ poscnt){
  int i = blockIdx.x * 256 + threadIdx.x;     // 0..4095
  const ulonglong2* p = (const ulonglong2*)(posw + (size_t)i * 64);
  int s = 0;
  #pragma unroll
  for (int k = 0; k < 32; ++k){
    ulonglong2 v = p[k];
    s += __popcll(v.x) + __popcll(v.y);
  }
  poscnt[i] = s;
}

// ---- kernel 4: tiny-K fused GEMM, round-3 launch envelope ----
// 256 threads / 4 waves, tile 128x128, grid 2048, r3-verified swizzle.
// A in registers (32 rows/wave x K=256 = 64 VGPR), B reg-staged to LDS
// in two 64-col halves, write-side XOR chunk swizzle, no per-K barriers.
__global__ __launch_bounds__(256) void gemm_kernel(const unsigned short* __restrict__ ctr,
                                                   const unsigned long long* __restrict__ posw,
                                                   float* __restrict__ total,
                                                   float* __restrict__ possum){
  __shared__ __align__(16) char Bl[32768];     // 64 cols x 512B, chunk-swizzled
  const int tid  = threadIdx.x;
  const int lane = tid & 63;
  const int w    = tid >> 6;                   // 0..3
  const int lr   = lane & 15, lk = lane >> 4;
  // round-3 verified block swizzle: grid 2048
  const int bid = (int)blockIdx.x;
  const int cb = (bid & 7) * 8 + ((bid >> 3) & 7);  // 0..63
  const int rb = bid >> 6;                          // 0..31
  const int i0 = rb << 7, n0 = cb << 7;
  const char* ctrB = (const char*)ctr;

  // ---- A fragments: 32 rows/wave x K=256 -> 16 x bf16x8, global->reg
  bf16x8 a[2][8];
  #pragma unroll
  for (int rt = 0; rt < 2; ++rt){
    int row = i0 + (w << 5) + (rt << 4) + lr;
    #pragma unroll
    for (int ks = 0; ks < 8; ++ks)
      a[rt][ks] = *(const bf16x8*)(ctrB + (size_t)row * 512 + (ks << 6) + (lk << 4));
  }

  const int rowb = i0 + (w << 5) + (lk << 2);  // + rt*16 + q = this lane's rows
  float tot[2][4], pos[2][4];
  #pragma unroll
  for (int rt = 0; rt < 2; ++rt)
    #pragma unroll
    for (int q = 0; q < 4; ++q){ tot[rt][q] = 0.f; pos[rt][q] = 0.f; }

  #pragma unroll
  for (int h = 0; h < 2; ++h){
    if (h) __syncthreads();                    // all reads of previous half done
    // ---- stage 64 cols x 512B: global->reg->LDS, swizzle on the WRITE side.
    // chunk p of col cl stored at position p^(cl&7) => read chunk c at c^(cl&7)
    #pragma unroll
    for (int j = 0; j < 8; ++j){
      int s  = (j << 8) + tid;                 // 16B slot 0..2047
      int cl = s >> 5;                         // local col 0..63
      int p  = s & 31;                         // source chunk 0..31
      uint4 v = *(const uint4*)(ctrB + (size_t)(n0 + (h << 6) + cl) * 512 + (p << 4));
      *(uint4*)(Bl + (cl << 9) + ((p ^ (cl & 7)) << 4)) = v;
    }
    __syncthreads();

    // pos bits for this 64-col half: bit nt4 of nibble (rt*4+q)
    const int widx = ((n0 & 4095) >> 6) + h;   // mod-B tiled pos word
    unsigned pbits = 0;
    #pragma unroll
    for (int rt = 0; rt < 2; ++rt)
      #pragma unroll
      for (int q = 0; q < 4; ++q){
        unsigned long long wv = posw[(size_t)(rowb + (rt << 4) + q) * 64 + widx];
        unsigned m4 = (unsigned)((wv >> lr) & 1ull)
                    | ((unsigned)((wv >> (16 + lr)) & 1ull) << 1)
                    | ((unsigned)((wv >> (32 + lr)) & 1ull) << 2)
                    | ((unsigned)((wv >> (48 + lr)) & 1ull) << 3);
        pbits |= m4 << (((rt << 2) + q) << 2);
      }

    #pragma unroll
    for (int nt4 = 0; nt4 < 4; ++nt4){
      const int cl  = (nt4 << 4) + lr;         // local col 0..63
      const char* bbase = Bl + (cl << 9);
      const int cx  = cl & 7;
      f32x4 acc0 = {0.f, 0.f, 0.f, 0.f};
      f32x4 acc1 = {0.f, 0.f, 0.f, 0.f};
      #pragma unroll
      for (int ks = 0; ks < 8; ++ks){
        bf16x8 b = *(const bf16x8*)(bbase + ((((ks << 2) + lk) ^ cx) << 4));
        acc0 = __builtin_amdgcn_mfma_f32_16x16x32_bf16(a[0][ks], b, acc0, 0, 0, 0);
        acc1 = __builtin_amdgcn_mfma_f32_16x16x32_bf16(a[1][ks], b, acc1, 0, 0, 0);
      }
      const int gcol = n0 + (h << 6) + cl;
      #pragma unroll
      for (int q = 0; q < 4; ++q){
        float e0 = fast_exp2(acc0[q] * EXP2SC);
        e0 = ((rowb + q) == gcol) ? 0.f : e0;
        tot[0][q] += e0;
        if ((pbits >> ((q << 2) + nt4)) & 1u) pos[0][q] += e0;
        float e1 = fast_exp2(acc1[q] * EXP2SC);
        e1 = ((rowb + 16 + q) == gcol) ? 0.f : e1;
        tot[1][q] += e1;
        if ((pbits >> (((4 + q) << 2) + nt4)) & 1u) pos[1][q] += e1;
      }
    }
  }

  // ---- reduce across lr (16 lanes) and one atomic pair per row ----
  #pragma unroll
  for (int rt = 0; rt < 2; ++rt){
    #pragma unroll
    for (int q = 0; q < 4; ++q){
      float v = tot[rt][q], u = pos[rt][q];
      v += __shfl_xor(v, 1); u += __shfl_xor(u, 1);
      v += __shfl_xor(v, 2); u += __shfl_xor(u, 2);
      v += __shfl_xor(v, 4); u += __shfl_xor(u, 4);
      v += __shfl_xor(v, 8); u += __shfl_xor(u, 8);
      if (lr == 0){
        int grow = rowb + (rt << 4) + q;
        atomicAdd(&total[grow], v);
        if (u != 0.f) atomicAdd(&possum[grow], u);
      }
    }
  }
}

// ---------------- kernel 5: finalize loss ----------------
__global__ __launch_bounds__(1024) void fin_kernel(const float* __restrict__ possum,
                                                   const float* __restrict__ total,
                                                   const int* __restrict__ poscnt,
                                                   const int* __restrict__ scnt,
                                                   float* __restrict__ out){
  int tid = threadIdx.x;
  float ls = 0.f, hc = 0.f;
  #pragma unroll
  for (int k = 0; k < 4; ++k){
    int i = k * 1024 + tid;
    int pii = (scnt[i] > 0) ? 1 : 0;
    int pm = 2 * poscnt[i] - pii;        // pos_m row count (self col removed)
    if (pm > 0){
      float ps = possum[i];
      float neg = total[i] - ps;
      ls += logf((ps + neg + 1e-8f) / ps);
      hc += 1.f;
    }
  }
  ls += __shfl_xor(ls, 1);  ls += __shfl_xor(ls, 2);  ls += __shfl_xor(ls, 4);
  ls += __shfl_xor(ls, 8);  ls += __shfl_xor(ls, 16); ls += __shfl_xor(ls, 32);
  hc += __shfl_xor(hc, 1);  hc += __shfl_xor(hc, 2);  hc += __shfl_xor(hc, 4);
  hc += __shfl_xor(hc, 8);  hc += __shfl_xor(hc, 16); hc += __shfl_xor(hc, 32);
  __shared__ float sl[16], sh[16];
  if ((tid & 63) == 0){ sl[tid >> 6] = ls; sh[tid >> 6] = hc; }
  __syncthreads();
  if (tid == 0){
    float S = 0.f, H = 0.f;
    #pragma unroll
    for (int w2 = 0; w2 < 16; ++w2){ S += sl[w2]; H += sh[w2]; }
    out[0] = S / fmaxf(H, 1.f);
  }
}

extern "C" void kernel_launch(void* const* d_in, const int* in_sizes, int n_in,
                              void* d_out, int out_size, void* d_ws, size_t ws_size,
                              hipStream_t stream){
  (void)in_sizes; (void)n_in; (void)out_size; (void)ws_size;
  const float* feat   = (const float*)d_in[0];
  const float* labels = (const float*)d_in[1];
  float* out = (float*)d_out;
  char* ws = (char*)d_ws;
  unsigned short* ctr       = (unsigned short*)(ws);               // 4,194,304 B
  unsigned long long* posw  = (unsigned long long*)(ws + 4194304); // 2,097,152 B
  ulonglong2* bits          = (ulonglong2*)(ws + 6291456);         //    65,536 B
  int* scnt                 = (int*)(ws + 6356992);                //    16,384 B
  float* possum             = (float*)(ws + 6373376);              //    16,384 B
  float* total              = (float*)(ws + 6389760);              //    16,384 B
  int* poscnt               = (int*)(ws + 6406144);                //    16,384 B

  // possum + total + poscnt contiguous: one async zero-fill
  hipMemsetAsync(possum, 0, 49152, stream);

  hipLaunchKernelGGL(pack_kernel, dim3(16),   dim3(256),  0, stream, labels, bits, scnt);
  hipLaunchKernelGGL(conv_kernel, dim3(1024), dim3(256),  0, stream, feat, ctr);
  hipLaunchKernelGGL(pos_kernel,  dim3(4096), dim3(256),  0, stream, bits, scnt, posw);
  hipLaunchKernelGGL(cnt_kernel,  dim3(16),   dim3(256),  0, stream, posw, poscnt);
  hipLaunchKernelGGL(gemm_kernel, dim3(2048), dim3(256),  0, stream, ctr, posw, total, possum);
  hipLaunchKernelGGL(fin_kernel,  dim3(1),    dim3(1024), 0, stream, possum, total, poscnt, scnt, out);
}